// Round 7
// baseline (328.170 us; speedup 1.0000x reference)
//
#include <hip/hip_runtime.h>
#include <math.h>

// ---------------------------------------------------------------------------
// SO3 convolution. bf16 MFMA GEMM (complex-as-real); Hermitian-half FFT/IFFT.
// Pipeline: k_fft_fwd (Hermitian bf16 out) -> k_wtr(wf) -> k_prep_B
//           -> k_beta_A -> memset(zhT) -> k_gemm (MFMA, atomic) -> k_wtr(wi)
//           -> k_inv2
// R8 lesson: fusing fft+prep spilled -- keep kernels separate.
// R9: wfT/wiT [bq][t][4] transposes -- big win in k_beta_A.
// R10: k_inv2 streamed FFT passes (VGPR 92->64), 8 blocks/CU -- 68->~40us.
// R11 NEUTRAL: depth-1 prefetch didn't move k_gemm (latency-bound, no TLP).
// R12: yhb in MFMA-fragment order; k_gemm no-LDS no-barrier -- ~49us.
// R13: o-quarter split, 1024 blocks -- Occ 13->27% but only -12% time:
// makespan is the l=15 K-chain (62 steps, latency-exposed), not residency.
// R14: k_inv2 packed-fp32 complex math + register twiddle chains -- <42us.
// R15: K-SPLIT k_gemm: kh2 halves the k-range -> 2048 blocks = 8/CU, l=15
// path 62->32 steps; halves accumulate via unsafeAtomicAdd (HW fadd, 2-way
// contention only); zhT zeroed by hipMemsetAsync after beta_A (zhT aliases
// Xfb/wfT, dead by then). Roofline here: 66MB traffic ~ 10.5us.
// Workspace: yhb 44.7MB | Ab 4.2MB | zh_T 11.2MB.
//   Xfb (8.4MB) + wfT (698KB) alias zh_T (lifetime fft->gemm, disjoint).
//   wiT (698KB) aliases yhb base (written after gemm, read by inv2).
// ---------------------------------------------------------------------------

typedef unsigned short u16;
typedef unsigned int   u32;
typedef __attribute__((ext_vector_type(8))) short  short8;   // 8 bf16
typedef __attribute__((ext_vector_type(4))) float  floatx4;
typedef __attribute__((ext_vector_type(2))) float  f32x2;

constexpr int LTOT = 5456;

constexpr int LB[17] = {0,1,10,35,84,165,286,455,680,969,
                        1330,1771,2300,2925,3654,4495,5456};

__device__ inline u16 f2bf(float f) {
    u32 u = __float_as_uint(f);
    u += 0x7fff + ((u >> 16) & 1);
    return (u16)(u >> 16);
}
__device__ inline u32 pack2bf(float re, float im) {
    return (u32)f2bf(re) | ((u32)f2bf(im) << 16);
}

// cc-dependent complex pack transform: cc=0 -> (re,-im) == b ^ 0x80000000;
// cc=1 -> (im,re) == ror16(b). Done as per-lane-constant perm + xor.
__device__ inline short8 btr4(uint4 q, u32 sel, u32 msk) {
    uint4 t;
    t.x = __builtin_amdgcn_perm(q.x, q.x, sel) ^ msk;
    t.y = __builtin_amdgcn_perm(q.y, q.y, sel) ^ msk;
    t.z = __builtin_amdgcn_perm(q.z, q.z, sel) ^ msk;
    t.w = __builtin_amdgcn_perm(q.w, q.w, sel) ^ msk;
    return *(short8*)&t;
}

// ---- packed-fp32 complex helpers (VOP3P). acc/result = (re, im) pairs. ----
__device__ __forceinline__ f32x2 cfma(f32x2 e, f32x2 t, f32x2 acc) {
    asm("v_pk_fma_f32 %0, %1, %2, %0 op_sel:[0,0,0] op_sel_hi:[0,1,1]\n\t"
        "v_pk_fma_f32 %0, %1, %2, %0 op_sel:[1,1,0] op_sel_hi:[1,0,1] neg_lo:[0,1,0]"
        : "+v"(acc) : "v"(e), "v"(t));
    return acc;
}
__device__ __forceinline__ f32x2 cmulp(f32x2 t, f32x2 r) {
    f32x2 d;
    asm("v_pk_mul_f32 %0, %1, %2 op_sel:[0,0] op_sel_hi:[0,1]\n\t"
        "v_pk_fma_f32 %0, %1, %2, %0 op_sel:[1,1,0] op_sel_hi:[1,0,1] neg_lo:[0,1,0]"
        : "=&v"(d) : "v"(t), "v"(r));
    return d;
}
__device__ __forceinline__ f32x2 fma_bl(f32x2 w2, f32x2 v, f32x2 acc) {
    asm("v_pk_fma_f32 %0, %1, %2, %0 op_sel:[0,0,0] op_sel_hi:[0,1,1]"
        : "+v"(acc) : "v"(w2), "v"(v));
    return acc;
}
__device__ __forceinline__ f32x2 fma_bh(f32x2 w2, f32x2 v, f32x2 acc) {
    asm("v_pk_fma_f32 %0, %1, %2, %0 op_sel:[1,0,0] op_sel_hi:[1,1,1]"
        : "+v"(acc) : "v"(w2), "v"(v));
    return acc;
}

// ---------------------------------------------------------------------------
// Wigner-table transpose: w[32][LTOT] -> wT[bq(8)][t][4] so a 4-beta group is
// one float4. Grid (22, 8) x 256.
// ---------------------------------------------------------------------------
__global__ __launch_bounds__(256) void k_wtr(const float* __restrict__ w,
                                             float* __restrict__ wT) {
    int t  = blockIdx.x * 256 + threadIdx.x;
    int bq = blockIdx.y;
    if (t < LTOT) {
        float4 v;
        v.x = w[(size_t)(bq * 4 + 0) * LTOT + t];
        v.y = w[(size_t)(bq * 4 + 1) * LTOT + t];
        v.z = w[(size_t)(bq * 4 + 2) * LTOT + t];
        v.w = w[(size_t)(bq * 4 + 3) * LTOT + t];
        *(float4*)(wT + ((size_t)bq * LTOT + t) * 4) = v;
    }
}

// ---------------------------------------------------------------------------
// Forward FFT2 (e^{-i}), radix-2 both passes, 512 threads, one task each.
// Stores ONLY Hermitian-half rows ma 0..15, bf16-packed.
// x: [z][i][b][a][g].   Xfb: [zi*32+b][ma(0..15)][ng] packed bf16 pairs.
// ---------------------------------------------------------------------------
__global__ __launch_bounds__(512) void k_fft_fwd(const float* __restrict__ x,
                                                 u32* __restrict__ Xfb) {
    __shared__ float xs[1056];               // [a][g] stride 33
    __shared__ float Gre[1056], Gim[1056];   // [a][k] stride 33
    __shared__ float Wc[32], Ws[32];
    int tid = threadIdx.x;
    if (tid < 32) {
        float sv, cv;
        sincosf(6.28318530717958647692f * (float)tid / 32.0f, &sv, &cv);
        Wc[tid] = cv; Ws[tid] = sv;
    }
    const float* src = x + (size_t)blockIdx.x * 1024;
    for (int e = tid; e < 1024; e += 512) xs[(e >> 5) * 33 + (e & 31)] = src[e];
    __syncthreads();
    // pass 1 over g (real input), radix-2: task = (a, k in 0..15)
    {
        int a = tid >> 4, k = tid & 15;
        const float* row = &xs[a * 33];
        float Er = 0.f, Ei = 0.f, Or = 0.f, Oi = 0.f;
#pragma unroll
        for (int h = 0; h < 16; h++) {
            int idx = (2 * h * k) & 31;
            float c = Wc[idx], s = Ws[idx];
            float xe = row[2 * h], xo = row[2 * h + 1];
            Er += xe * c;  Ei -= xe * s;
            Or += xo * c;  Oi -= xo * s;
        }
        float WOr = Or * Wc[k] + Oi * Ws[k];
        float WOi = Oi * Wc[k] - Or * Ws[k];
        Gre[a * 33 + k]      = Er + WOr;
        Gim[a * 33 + k]      = Ei + WOi;
        Gre[a * 33 + k + 16] = Er - WOr;
        Gim[a * 33 + k + 16] = Ei - WOi;
    }
    __syncthreads();
    // pass 2 over a, radix-2 combine; store only row ma (0..15)
    {
        u32* dst = Xfb + (size_t)blockIdx.x * 512;
        int ng = tid & 31, ma = tid >> 5;
        float Er = 0.f, Ei = 0.f, Or = 0.f, Oi = 0.f;
#pragma unroll
        for (int h = 0; h < 16; h++) {
            int idx = (2 * h * ma) & 31;
            float c = Wc[idx], s = Ws[idx];
            float er = Gre[(2 * h) * 33 + ng],      ei = Gim[(2 * h) * 33 + ng];
            float orr = Gre[(2 * h + 1) * 33 + ng], oi = Gim[(2 * h + 1) * 33 + ng];
            Er += er * c + ei * s;   Ei += ei * c - er * s;
            Or += orr * c + oi * s;  Oi += oi * c - orr * s;
        }
        float WOr = Or * Wc[ma] + Oi * Ws[ma];
        float WOi = Oi * Wc[ma] - Or * Ws[ma];
        dst[ma * 32 + ng] = pack2bf(Er + WOr, Ei + WOi);
    }
}

// ---------------------------------------------------------------------------
// Build compact bf16 yh in MFMA-FRAGMENT ORDER (R12):
// io = (i,o): i = ih*16+kh*4+j, o = oh*32+nt*8+ph
// nio = ih*1024 + oh*512 + nt*128 + kh*32 + ph*4 + j
// so k_gemm's lane fragment (4 words j=0..3) is one contiguous uint4.
// ---------------------------------------------------------------------------
__global__ __launch_bounds__(256) void k_prep_B(const float* __restrict__ Dre,
                                                const float* __restrict__ Dim,
                                                const float* __restrict__ ker,
                                                u32* __restrict__ yhb) {
    __shared__ float Ds[8][24];
    int t0  = blockIdx.x * 8;
    int tid = threadIdx.x;
    if (tid < 192) {
        int rr = tid / 24, jj = tid - rr * 24;
        Ds[rr][jj] = (jj < 12) ? Dre[(t0 + rr) * 12 + jj] : Dim[(t0 + rr) * 12 + jj - 12];
    }
    __syncthreads();
    for (int rep = 0; rep < 8; rep++) {
        int io = rep * 256 + tid;
        int i  = io >> 6, o = io & 63;
        int nio = ((i >> 4) << 10) + ((o >> 5) << 9) + (((o >> 3) & 3) << 7)
                + (((i >> 2) & 3) << 5) + ((o & 7) << 2) + (i & 3);
        const float4* kp = (const float4*)(ker + io * 12);
        float4 ka = kp[0], kb = kp[1], kc = kp[2];
        float kv[12] = {ka.x, ka.y, ka.z, ka.w, kb.x, kb.y, kb.z, kb.w,
                        kc.x, kc.y, kc.z, kc.w};
#pragma unroll
        for (int rr = 0; rr < 8; rr++) {
            float sr = 0.f, si = 0.f;
#pragma unroll
            for (int j = 0; j < 12; j++) {
                sr += Ds[rr][j]      * kv[j];
                si += Ds[rr][12 + j] * kv[j];
            }
            yhb[(size_t)(t0 + rr) * 2048 + nio] = pack2bf(sr, si);
        }
    }
}

// ---------------------------------------------------------------------------
// Fused beta-contraction + bf16 A-fragment pack. Xfb is Hermitian-half:
// rows ma 0..15 stored; ma>=17 read as conj(Xf[32-ma][(32-ng)&31]).
// Grid: (ma 32) x (zig 64) = 2048 blocks; thread = (zil 2, lq 4, ng 32).
// R9: b-loop grouped in beta-quads; wfT[bq][t][4] gives one float4 per
// (bq, l) instead of 4 scalar strided loads.
// ---------------------------------------------------------------------------
__global__ __launch_bounds__(256) void k_beta_A(const u32* __restrict__ Xfb,
                                                const float* __restrict__ wfT,
                                                u16* __restrict__ Ab) {
    int ma  = blockIdx.x >> 6;
    int zig = blockIdx.x & 63;
    int tid = threadIdx.x;
    int ng  = tid & 31;
    int lq  = (tid >> 5) & 3;
    int zil = tid >> 7;
    int zi  = zig * 2 + zil;
    int z = zi >> 5, i = zi & 31;
    int mh = (ma <= 15) ? ma : ma - 32;
    int nh = (ng <= 15) ? ng : ng - 32;
    int am = mh < 0 ? -mh : mh;
    int an = nh < 0 ? -nh : nh;
    int l0 = am > an ? am : an;
    int lb = lq * 4;

    int isconj = (ma > 16);
    int mau = isconj ? (32 - ma) : ma;
    int ngu = isconj ? ((32 - ng) & 31) : ng;
    if (mau > 15) { mau = 0; ngu = 0; }   // ma==16: l0==16, values unused

    int tl[4];
#pragma unroll
    for (int j = 0; j < 4; j++) {
        int l = lb + j;
        tl[j] = LB[l] + (mh + l) * (2 * l + 1) + (nh + l);
    }
    float2 acc[4];
#pragma unroll
    for (int j = 0; j < 4; j++) acc[j] = make_float2(0.f, 0.f);

    const u32* xp = Xfb + (size_t)zi * 32 * 512 + mau * 32 + ngu;
    float sgn = isconj ? -1.f : 1.f;
#pragma unroll 2
    for (int bq = 0; bq < 8; bq++) {
        u32 p0 = xp[(size_t)(4 * bq + 0) * 512];
        u32 p1 = xp[(size_t)(4 * bq + 1) * 512];
        u32 p2 = xp[(size_t)(4 * bq + 2) * 512];
        u32 p3 = xp[(size_t)(4 * bq + 3) * 512];
        float vx0 = __uint_as_float(p0 << 16);
        float vy0 = sgn * __uint_as_float(p0 & 0xffff0000u);
        float vx1 = __uint_as_float(p1 << 16);
        float vy1 = sgn * __uint_as_float(p1 & 0xffff0000u);
        float vx2 = __uint_as_float(p2 << 16);
        float vy2 = sgn * __uint_as_float(p2 & 0xffff0000u);
        float vx3 = __uint_as_float(p3 << 16);
        float vy3 = sgn * __uint_as_float(p3 & 0xffff0000u);
        const float4* wq = (const float4*)(wfT + (size_t)bq * (LTOT * 4));
#pragma unroll
        for (int j = 0; j < 4; j++) {
            if (lb + j >= l0) {
                float4 w = wq[tl[j]];
                acc[j].x += w.x * vx0 + w.y * vx1 + w.z * vx2 + w.w * vx3;
                acc[j].y += w.x * vy0 + w.y * vy1 + w.z * vy2 + w.w * vy3;
            }
        }
    }
    int s_i  = i >> 4;
    int kl   = 2 * (i & 15);
    int joff = kl & 7;
    int Lhi  = (kl >> 3) << 4;
#pragma unroll
    for (int j = 0; j < 4; j++) {
        int l = lb + j;
        if (l >= l0) {
            int mi = mh + l, ni = nh + l;
            int s   = 2 * ni + s_i;
            int row = 4 * mi + z;
            u32 pack = pack2bf(acc[j].x, acc[j].y);
            size_t off = (size_t)8192 * l * l + (size_t)s * 4096
                       + ((row >> 4) << 9) + ((Lhi + (row & 15)) << 3) + joff;
            *(u32*)(Ab + off) = pack;
        }
    }
}

// ---------------------------------------------------------------------------
// MFMA GEMM, R15: K-split. 2048 blocks = sum_l 8*(2l+1), big l first:
// block = (l, n, oq, kh2). kh2 halves the k-range (even step counts:
// [0, 2*ceil(nl/2)) / [2*ceil(nl/2), 2*nl)). NO LDS, NO barriers;
// B-fragments contiguous uint4 from fragment-ordered yhb; per-lane perm+xor
// complex transform; 2-deep register pipeline, unconditional tail prefetch
// (OOB reads stay inside the 60MB workspace; values dead).
// Both k-halves unsafeAtomicAdd into pre-zeroed zh_T[zo][t] (float pairs).
// ---------------------------------------------------------------------------
__global__ __launch_bounds__(256, 8) void k_gemm(const u16* __restrict__ Ab,
                                                 const u32* __restrict__ yhb,
                                                 float* __restrict__ zhT) {
    int rem = blockIdx.x, l, nl = 1;
    for (l = 15; l >= 0; l--) {
        nl = 2 * l + 1;
        int c = nl * 8;
        if (rem < c) break;
        rem -= c;
    }
    int kh2 = rem & 1;
    int oq  = (rem >> 1) & 3;
    int n   = rem >> 3;
    int base = LB[l];
    const u16* Ag = Ab + (size_t)8192 * l * l;
    int khalf = (nl + 1) >> 1;
    int s0    = kh2 ? 2 * khalf : 0;
    int s_end = kh2 ? 2 * nl    : 2 * khalf;

    int tid = threadIdx.x, lane = tid & 63, w = tid >> 6;
    int cc = lane & 1;
    u32 sel = cc ? 0x01000302u : 0x03020100u;   // ror16 : identity
    u32 msk = cc ? 0u          : 0x80000000u;   // 0     : negate-hi

    const u32* Bb = yhb + (size_t)(base + n) * 2048 + (oq << 8) + ((lane >> 1) << 2);
    const u16* Aw = Ag + ((w << 10) | (lane << 3));

    floatx4 acc[2][2];
#pragma unroll
    for (int a = 0; a < 2; a++)
#pragma unroll
        for (int b = 0; b < 2; b++) acc[a][b] = (floatx4)0.f;

#define LOADB(s, q0, q1) { \
    const uint4* bp = (const uint4*)(Bb + (size_t)((s) >> 1) * nl * 2048 + (((s) & 1) << 10)); \
    q0 = bp[0]; q1 = bp[32]; }
#define LOADA(s, r0, r1) { \
    const u16* apx = Aw + (size_t)(s) * 4096; \
    r0 = *(const short8*)apx; r1 = *(const short8*)(apx + 512); }
#define MF(a, b, c) __builtin_amdgcn_mfma_f32_16x16x32_bf16(a, b, c, 0, 0, 0)

    uint4 eB0, eB1; short8 ea0, ea1;   // even-step raw
    uint4 oB0, oB1; short8 oa0, oa1;   // odd-step raw
    LOADA(s0, ea0, ea1);     LOADB(s0, eB0, eB1);
    LOADA(s0 + 1, oa0, oa1); LOADB(s0 + 1, oB0, oB1);

    for (int s = s0; s < s_end; s += 2) {
        // even step: transform (waits on its loads), refill regs, then MFMA
        short8 bf0 = btr4(eB0, sel, msk), bf1 = btr4(eB1, sel, msk);
        short8 af0 = ea0, af1 = ea1;
        LOADA(s + 2, ea0, ea1); LOADB(s + 2, eB0, eB1);
        acc[0][0] = MF(af0, bf0, acc[0][0]);  acc[1][0] = MF(af1, bf0, acc[1][0]);
        acc[0][1] = MF(af0, bf1, acc[0][1]);  acc[1][1] = MF(af1, bf1, acc[1][1]);
        // odd step
        short8 cf0 = btr4(oB0, sel, msk), cf1 = btr4(oB1, sel, msk);
        short8 ag0 = oa0, ag1 = oa1;
        LOADA(s + 3, oa0, oa1); LOADB(s + 3, oB0, oB1);
        acc[0][0] = MF(ag0, cf0, acc[0][0]);  acc[1][0] = MF(ag1, cf0, acc[1][0]);
        acc[0][1] = MF(ag0, cf1, acc[0][1]);  acc[1][1] = MF(ag1, cf1, acc[1][1]);
    }
#undef LOADB
#undef LOADA
#undef MF

    int q = lane >> 4, cn = lane & 15;
#pragma unroll
    for (int mt = 0; mt < 2; mt++) {
#pragma unroll
        for (int nt = 0; nt < 2; nt++) {
            int nu2 = (nt << 4) + cn;
            int o2  = (oq << 4) + (nu2 >> 1);
            int c2  = nu2 & 1;
#pragma unroll
            for (int r = 0; r < 4; r++) {
                int R = (w << 5) + (mt << 4) + (q << 2) + r;
                int m = R >> 2, z = R & 3;
                if (m < nl) {
                    int t  = base + m * nl + n;
                    int zo = (z << 6) + o2;
                    unsafeAtomicAdd(&zhT[((size_t)zo * LTOT + t) * 2 + c2],
                                    acc[mt][nt][r]);
                }
            }
        }
    }
}

// ---------------------------------------------------------------------------
// Inverse, 4 betas per block. R14: packed-fp32 complex math throughout.
// gather: v_pk_fma broadcast MACs; pass 1: register twiddle rotation chains,
// zero twiddle LDS; pass 2: 135->15 LDS ops/task via chains + symmetries.
// Grid: 2048 = (bq 8) x (zo 256); 256 thr; ~17.7KB LDS.
// ---------------------------------------------------------------------------
__global__ __launch_bounds__(256, 8) void k_inv2(const float2* __restrict__ zhT,
                                                 const float* __restrict__ wiT,
                                                 const float* __restrict__ bias,
                                                 float* __restrict__ out) {
    __shared__ __align__(16) f32x2 Pb[4 * 544];  // plane p at p*544, rows stride 34
    __shared__ f32x2 Wf[32];                     // (cos, sin) 2pi i/32
    int tid = threadIdx.x;
    int zo = blockIdx.x & 255;
    int bq = blockIdx.x >> 8;
    int b0 = bq * 4;
    if (tid < 32) {
        float sv, cv;
        sincosf(6.28318530717958647692f * (float)tid / 32.0f, &sv, &cv);
        f32x2 wv; wv.x = cv; wv.y = sv;
        Wf[tid] = wv;
    }
    // ---- gather: thread = (ng 32, rq 8); 2 ma-rows; 4 betas share each zv
    {
        int ng = tid & 31, rq = tid >> 5;
        int nh = (ng <= 15) ? ng : ng - 32;
        int an = nh < 0 ? -nh : nh;
        const f32x2* zr = (const f32x2*)zhT + (size_t)zo * LTOT;
        const f32x2* wp = (const f32x2*)wiT + (size_t)bq * (LTOT * 2);
#pragma unroll
        for (int mr = 0; mr < 2; mr++) {
            int ma = rq + 8 * mr;
            int l0 = ma > an ? ma : an;
            f32x2 a0 = (f32x2)0.f, a1 = a0, a2 = a0, a3 = a0;
#pragma unroll 4
            for (int l = 0; l < 16; l++) {
                if (l >= l0) {
                    int t = LB[l] + (ma + l) * (2 * l + 1) + (nh + l);
                    f32x2 zv = zr[t];
                    f32x2 w01 = wp[2 * t], w23 = wp[2 * t + 1];
                    a0 = fma_bl(w01, zv, a0);
                    a1 = fma_bh(w01, zv, a1);
                    a2 = fma_bl(w23, zv, a2);
                    a3 = fma_bh(w23, zv, a3);
                }
            }
            int po = ma * 34 + ng;
            Pb[po]            = a0;
            Pb[544 + po]      = a1;
            Pb[2 * 544 + po]  = a2;
            Pb[3 * 544 + po]  = a3;
        }
    }
    __syncthreads();
    // ---- pass 1 (ng -> g): 64 rows x 8 q = 512 tasks over 2 rounds.
#pragma unroll
    for (int it = 0; it < 2; it++) {
        int task = tid + it * 256;
        int rowid = task >> 3, q = task & 7;
        f32x2* prow = &Pb[(rowid >> 4) * 544 + (rowid & 15) * 34];
        const floatx4* prow4 = (const floatx4*)prow;
        floatx4 eo0 = prow4[0];
        f32x2 Ep; Ep.x = eo0.x; Ep.y = eo0.y;
        f32x2 Op; Op.x = eo0.z; Op.y = eo0.w;
        f32x2 En = (f32x2)0.f, On = (f32x2)0.f;
        f32x2 r = Wf[2 * q];
        f32x2 t = r;
#pragma unroll
        for (int h = 1; h < 16; h++) {
            floatx4 eo = prow4[h];
            f32x2 e; e.x = eo.x; e.y = eo.y;
            f32x2 o; o.x = eo.z; o.y = eo.w;
            if (h & 1) { En = cfma(e, t, En); On = cfma(o, t, On); }
            else       { Ep = cfma(e, t, Ep); Op = cfma(o, t, Op); }
            if (h < 15) t = cmulp(t, r);
        }
        f32x2 E0 = Ep + En, E1 = Ep - En;
        f32x2 O0 = Op + On, O1 = Op - On;
        f32x2 wq = Wf[q];
        f32x2 w0 = cmulp(O0, wq);
        f32x2 u1 = cmulp(O1, wq);
        f32x2 w1; w1.x = -u1.y; w1.y = u1.x;     // i * u1  (W^{q+8} = i W^q)
        prow[q]      = E0 + w0;
        prow[q + 16] = E0 - w0;
        prow[q + 8]  = E1 + w1;
        prow[q + 24] = E1 - w1;
    }
    __syncthreads();
    // ---- pass 2 (ma -> a): tasks (p, qa, g) x4 rounds; direct store + bias
    float bv = bias[zo & 63];
#pragma unroll
    for (int it = 0; it < 4; it++) {
        int task = tid + it * 256;
        int p = task >> 8, rr = task & 255;
        int qa = rr >> 5, g = rr & 31;
        const f32x2* pc = &Pb[p * 544];
        f32x2 r = Wf[2 * qa];
        f32x2 u = Wf[qa];
        f32x2 Uee = (f32x2)0.f, Ueo = Uee, Ve = Uee, Vo = Uee;
        f32x2 c0 = pc[g];
        {   // j = 0: odd column only
            f32x2 c1 = pc[34 + g];
            Ve = cfma(c1, u, Ve);
        }
        f32x2 t = r;
        u = cmulp(u, r);
#pragma unroll
        for (int j = 1; j < 8; j++) {
            f32x2 ce = pc[(2 * j) * 34 + g];
            f32x2 co = pc[(2 * j + 1) * 34 + g];
            if (j & 1) { Ueo = cfma(ce, t, Ueo); Vo = cfma(co, u, Vo); }
            else       { Uee = cfma(ce, t, Uee); Ve = cfma(co, u, Ve); }
            if (j < 7) { t = cmulp(t, r); u = cmulp(u, r); }
        }
        float EaA = c0.x + 2.f * (Uee.x + Ueo.x);
        float EaB = c0.x + 2.f * (Uee.x - Ueo.x);
        float OaA = 2.f * (Ve.x + Vo.x);
        float OaB = -2.f * (Ve.y - Vo.y);
        float* dst = out + (size_t)zo * 32768 + (size_t)(b0 + p) * 1024;
        constexpr float sc = 1.f / 1024.f;
        dst[qa * 32 + g]         = (EaA + OaA) * sc + bv;
        dst[(qa + 16) * 32 + g]  = (EaA - OaA) * sc + bv;
        dst[(qa + 8) * 32 + g]   = (EaB + OaB) * sc + bv;
        dst[(qa + 24) * 32 + g]  = (EaB - OaB) * sc + bv;
    }
}

// ---------------------------------------------------------------------------
extern "C" void kernel_launch(void* const* d_in, const int* in_sizes, int n_in,
                              void* d_out, int out_size, void* d_ws, size_t ws_size,
                              hipStream_t stream) {
    const float* x    = (const float*)d_in[0];
    const float* ker  = (const float*)d_in[1];
    const float* bias = (const float*)d_in[2];
    const float* wf   = (const float*)d_in[3];
    const float* wi   = (const float*)d_in[4];
    const float* Dre  = (const float*)d_in[5];
    const float* Dim  = (const float*)d_in[6];
    float* out = (float*)d_out;

    // layout: yhb 44.7MB | Ab 4.2MB | zh_T 11.2MB.
    // Xfb (8.4MB) + wfT (698KB, at zhT+8.39MB) alias zh_T: both dead once
    // zhT is zeroed (after k_beta_A). wiT (698KB) aliases yhb base: written
    // after k_gemm (yhb dead), read by k_inv2.
    char* ws = (char*)d_ws;
    u32*    yhb = (u32*)ws;
    u16*    Ab  = (u16*)(ws + 44695552);
    float*  zhT = (float*)(ws + 44695552 + 4194304);
    u32*    Xfb = (u32*)zhT;                                    // disjoint lifetime vs zh_T
    float*  wfT = (float*)(ws + 44695552 + 4194304 + 8388608);  // zhT tail, pre-gemm
    float*  wiT = (float*)ws;                                   // yhb region, post-gemm

    hipLaunchKernelGGL(k_fft_fwd, dim3(4096),  dim3(512), 0, stream, x, Xfb);
    hipLaunchKernelGGL(k_wtr,     dim3(22, 8), dim3(256), 0, stream, wf, wfT);
    hipLaunchKernelGGL(k_prep_B,  dim3(682),   dim3(256), 0, stream, Dre, Dim, ker, yhb);
    hipLaunchKernelGGL(k_beta_A,  dim3(2048),  dim3(256), 0, stream, Xfb, wfT, Ab);
    hipMemsetAsync(zhT, 0, (size_t)256 * LTOT * 2 * sizeof(float), stream);
    hipLaunchKernelGGL(k_gemm,    dim3(2048),  dim3(256), 0, stream, Ab, yhb, zhT);
    hipLaunchKernelGGL(k_wtr,     dim3(22, 8), dim3(256), 0, stream, wi, wiT);
    hipLaunchKernelGGL(k_inv2,    dim3(2048),  dim3(256), 0, stream,
                       (const float2*)zhT, wiT, bias, out);
}

// Round 8
// 236.478 us; speedup vs baseline: 1.3877x; 1.3877x over previous
//
#include <hip/hip_runtime.h>
#include <math.h>

// ---------------------------------------------------------------------------
// SO3 convolution. bf16 MFMA GEMM (complex-as-real); Hermitian-half FFT/IFFT.
// Pipeline: k_fft_fwd -> k_wtr(wf) -> k_prep_B -> k_beta_A
//           -> k_gemm (MFMA, K-split, 2 buffers) -> k_red -> k_wtr(wi) -> k_inv2
// R8 lesson: fusing fft+prep spilled -- keep kernels separate.
// R9: wfT/wiT [bq][t][4] transposes -- big win in k_beta_A.
// R10: k_inv2 streamed FFT passes (VGPR 92->64), 8 blocks/CU -- 68->~40us.
// R11 NEUTRAL: depth-1 prefetch didn't move k_gemm (latency-bound, no TLP).
// R12: yhb in MFMA-fragment order; k_gemm no-LDS no-barrier -- ~49us.
// R13: o-quarter split, 1024 blocks -- Occ 13->27%, -12% time only.
// R14: k_inv2 packed-fp32 complex math + register twiddle chains -- <42us.
// R15 DISASTER: K-split w/ unsafeAtomicAdd = 155us. 8.4M scattered
// device-scope f32 atomics ~ 54G/s ceiling; WRITE_SIZE 3x (RMW). NEVER
// use scattered atomics for a 2-way reduction on gfx950.
// R16: keep K-split (chain 62->32 steps, 2048 blocks = 8/CU) but each
// k-half writes a COMPLETE partial tile with plain stores: kh2=0 -> zhT,
// kh2=1 -> d_out (scratch until k_inv2); k_red sums (33MB, L2-hot, ~5us).
// XCD swizzle: orig=(d&255)*8+(d>>8) puts the 8 (oq,kh2) siblings sharing
// one A-panel on one XCD (same dispatch idx mod 8).
// Workspace: yhb 44.7MB | Ab 4.2MB | zh_T 11.2MB.
//   Xfb (8.4MB) + wfT (698KB) alias zh_T (lifetime fft->gemm, disjoint).
//   wiT (698KB) aliases yhb base (written after gemm, read by inv2).
//   zhT1 = d_out (33.5MB out, fully overwritten by k_inv2 at the end).
// ---------------------------------------------------------------------------

typedef unsigned short u16;
typedef unsigned int   u32;
typedef __attribute__((ext_vector_type(8))) short  short8;   // 8 bf16
typedef __attribute__((ext_vector_type(4))) float  floatx4;
typedef __attribute__((ext_vector_type(2))) float  f32x2;

constexpr int LTOT = 5456;

constexpr int LB[17] = {0,1,10,35,84,165,286,455,680,969,
                        1330,1771,2300,2925,3654,4495,5456};

__device__ inline u16 f2bf(float f) {
    u32 u = __float_as_uint(f);
    u += 0x7fff + ((u >> 16) & 1);
    return (u16)(u >> 16);
}
__device__ inline u32 pack2bf(float re, float im) {
    return (u32)f2bf(re) | ((u32)f2bf(im) << 16);
}

// cc-dependent complex pack transform: cc=0 -> (re,-im) == b ^ 0x80000000;
// cc=1 -> (im,re) == ror16(b). Done as per-lane-constant perm + xor.
__device__ inline short8 btr4(uint4 q, u32 sel, u32 msk) {
    uint4 t;
    t.x = __builtin_amdgcn_perm(q.x, q.x, sel) ^ msk;
    t.y = __builtin_amdgcn_perm(q.y, q.y, sel) ^ msk;
    t.z = __builtin_amdgcn_perm(q.z, q.z, sel) ^ msk;
    t.w = __builtin_amdgcn_perm(q.w, q.w, sel) ^ msk;
    return *(short8*)&t;
}

// ---- packed-fp32 complex helpers (VOP3P). acc/result = (re, im) pairs. ----
__device__ __forceinline__ f32x2 cfma(f32x2 e, f32x2 t, f32x2 acc) {
    asm("v_pk_fma_f32 %0, %1, %2, %0 op_sel:[0,0,0] op_sel_hi:[0,1,1]\n\t"
        "v_pk_fma_f32 %0, %1, %2, %0 op_sel:[1,1,0] op_sel_hi:[1,0,1] neg_lo:[0,1,0]"
        : "+v"(acc) : "v"(e), "v"(t));
    return acc;
}
__device__ __forceinline__ f32x2 cmulp(f32x2 t, f32x2 r) {
    f32x2 d;
    asm("v_pk_mul_f32 %0, %1, %2 op_sel:[0,0] op_sel_hi:[0,1]\n\t"
        "v_pk_fma_f32 %0, %1, %2, %0 op_sel:[1,1,0] op_sel_hi:[1,0,1] neg_lo:[0,1,0]"
        : "=&v"(d) : "v"(t), "v"(r));
    return d;
}
__device__ __forceinline__ f32x2 fma_bl(f32x2 w2, f32x2 v, f32x2 acc) {
    asm("v_pk_fma_f32 %0, %1, %2, %0 op_sel:[0,0,0] op_sel_hi:[0,1,1]"
        : "+v"(acc) : "v"(w2), "v"(v));
    return acc;
}
__device__ __forceinline__ f32x2 fma_bh(f32x2 w2, f32x2 v, f32x2 acc) {
    asm("v_pk_fma_f32 %0, %1, %2, %0 op_sel:[1,0,0] op_sel_hi:[1,1,1]"
        : "+v"(acc) : "v"(w2), "v"(v));
    return acc;
}

// ---------------------------------------------------------------------------
// Wigner-table transpose: w[32][LTOT] -> wT[bq(8)][t][4] so a 4-beta group is
// one float4. Grid (22, 8) x 256.
// ---------------------------------------------------------------------------
__global__ __launch_bounds__(256) void k_wtr(const float* __restrict__ w,
                                             float* __restrict__ wT) {
    int t  = blockIdx.x * 256 + threadIdx.x;
    int bq = blockIdx.y;
    if (t < LTOT) {
        float4 v;
        v.x = w[(size_t)(bq * 4 + 0) * LTOT + t];
        v.y = w[(size_t)(bq * 4 + 1) * LTOT + t];
        v.z = w[(size_t)(bq * 4 + 2) * LTOT + t];
        v.w = w[(size_t)(bq * 4 + 3) * LTOT + t];
        *(float4*)(wT + ((size_t)bq * LTOT + t) * 4) = v;
    }
}

// ---------------------------------------------------------------------------
// Partial-sum reduce: zhT += zhT1. 698368 float4 = 2728 x 256.
// ---------------------------------------------------------------------------
__global__ __launch_bounds__(256) void k_red(float4* __restrict__ a,
                                             const float4* __restrict__ b) {
    size_t i = (size_t)blockIdx.x * 256 + threadIdx.x;
    float4 va = a[i], vb = b[i];
    va.x += vb.x; va.y += vb.y; va.z += vb.z; va.w += vb.w;
    a[i] = va;
}

// ---------------------------------------------------------------------------
// Forward FFT2 (e^{-i}), radix-2 both passes, 512 threads, one task each.
// Stores ONLY Hermitian-half rows ma 0..15, bf16-packed.
// x: [z][i][b][a][g].   Xfb: [zi*32+b][ma(0..15)][ng] packed bf16 pairs.
// ---------------------------------------------------------------------------
__global__ __launch_bounds__(512) void k_fft_fwd(const float* __restrict__ x,
                                                 u32* __restrict__ Xfb) {
    __shared__ float xs[1056];               // [a][g] stride 33
    __shared__ float Gre[1056], Gim[1056];   // [a][k] stride 33
    __shared__ float Wc[32], Ws[32];
    int tid = threadIdx.x;
    if (tid < 32) {
        float sv, cv;
        sincosf(6.28318530717958647692f * (float)tid / 32.0f, &sv, &cv);
        Wc[tid] = cv; Ws[tid] = sv;
    }
    const float* src = x + (size_t)blockIdx.x * 1024;
    for (int e = tid; e < 1024; e += 512) xs[(e >> 5) * 33 + (e & 31)] = src[e];
    __syncthreads();
    // pass 1 over g (real input), radix-2: task = (a, k in 0..15)
    {
        int a = tid >> 4, k = tid & 15;
        const float* row = &xs[a * 33];
        float Er = 0.f, Ei = 0.f, Or = 0.f, Oi = 0.f;
#pragma unroll
        for (int h = 0; h < 16; h++) {
            int idx = (2 * h * k) & 31;
            float c = Wc[idx], s = Ws[idx];
            float xe = row[2 * h], xo = row[2 * h + 1];
            Er += xe * c;  Ei -= xe * s;
            Or += xo * c;  Oi -= xo * s;
        }
        float WOr = Or * Wc[k] + Oi * Ws[k];
        float WOi = Oi * Wc[k] - Or * Ws[k];
        Gre[a * 33 + k]      = Er + WOr;
        Gim[a * 33 + k]      = Ei + WOi;
        Gre[a * 33 + k + 16] = Er - WOr;
        Gim[a * 33 + k + 16] = Ei - WOi;
    }
    __syncthreads();
    // pass 2 over a, radix-2 combine; store only row ma (0..15)
    {
        u32* dst = Xfb + (size_t)blockIdx.x * 512;
        int ng = tid & 31, ma = tid >> 5;
        float Er = 0.f, Ei = 0.f, Or = 0.f, Oi = 0.f;
#pragma unroll
        for (int h = 0; h < 16; h++) {
            int idx = (2 * h * ma) & 31;
            float c = Wc[idx], s = Ws[idx];
            float er = Gre[(2 * h) * 33 + ng],      ei = Gim[(2 * h) * 33 + ng];
            float orr = Gre[(2 * h + 1) * 33 + ng], oi = Gim[(2 * h + 1) * 33 + ng];
            Er += er * c + ei * s;   Ei += ei * c - er * s;
            Or += orr * c + oi * s;  Oi += oi * c - orr * s;
        }
        float WOr = Or * Wc[ma] + Oi * Ws[ma];
        float WOi = Oi * Wc[ma] - Or * Ws[ma];
        dst[ma * 32 + ng] = pack2bf(Er + WOr, Ei + WOi);
    }
}

// ---------------------------------------------------------------------------
// Build compact bf16 yh in MFMA-FRAGMENT ORDER (R12):
// io = (i,o): i = ih*16+kh*4+j, o = oh*32+nt*8+ph
// nio = ih*1024 + oh*512 + nt*128 + kh*32 + ph*4 + j
// so k_gemm's lane fragment (4 words j=0..3) is one contiguous uint4.
// ---------------------------------------------------------------------------
__global__ __launch_bounds__(256) void k_prep_B(const float* __restrict__ Dre,
                                                const float* __restrict__ Dim,
                                                const float* __restrict__ ker,
                                                u32* __restrict__ yhb) {
    __shared__ float Ds[8][24];
    int t0  = blockIdx.x * 8;
    int tid = threadIdx.x;
    if (tid < 192) {
        int rr = tid / 24, jj = tid - rr * 24;
        Ds[rr][jj] = (jj < 12) ? Dre[(t0 + rr) * 12 + jj] : Dim[(t0 + rr) * 12 + jj - 12];
    }
    __syncthreads();
    for (int rep = 0; rep < 8; rep++) {
        int io = rep * 256 + tid;
        int i  = io >> 6, o = io & 63;
        int nio = ((i >> 4) << 10) + ((o >> 5) << 9) + (((o >> 3) & 3) << 7)
                + (((i >> 2) & 3) << 5) + ((o & 7) << 2) + (i & 3);
        const float4* kp = (const float4*)(ker + io * 12);
        float4 ka = kp[0], kb = kp[1], kc = kp[2];
        float kv[12] = {ka.x, ka.y, ka.z, ka.w, kb.x, kb.y, kb.z, kb.w,
                        kc.x, kc.y, kc.z, kc.w};
#pragma unroll
        for (int rr = 0; rr < 8; rr++) {
            float sr = 0.f, si = 0.f;
#pragma unroll
            for (int j = 0; j < 12; j++) {
                sr += Ds[rr][j]      * kv[j];
                si += Ds[rr][12 + j] * kv[j];
            }
            yhb[(size_t)(t0 + rr) * 2048 + nio] = pack2bf(sr, si);
        }
    }
}

// ---------------------------------------------------------------------------
// Fused beta-contraction + bf16 A-fragment pack. Xfb is Hermitian-half:
// rows ma 0..15 stored; ma>=17 read as conj(Xf[32-ma][(32-ng)&31]).
// Grid: (ma 32) x (zig 64) = 2048 blocks; thread = (zil 2, lq 4, ng 32).
// R9: b-loop grouped in beta-quads; wfT[bq][t][4] gives one float4 per
// (bq, l) instead of 4 scalar strided loads.
// ---------------------------------------------------------------------------
__global__ __launch_bounds__(256) void k_beta_A(const u32* __restrict__ Xfb,
                                                const float* __restrict__ wfT,
                                                u16* __restrict__ Ab) {
    int ma  = blockIdx.x >> 6;
    int zig = blockIdx.x & 63;
    int tid = threadIdx.x;
    int ng  = tid & 31;
    int lq  = (tid >> 5) & 3;
    int zil = tid >> 7;
    int zi  = zig * 2 + zil;
    int z = zi >> 5, i = zi & 31;
    int mh = (ma <= 15) ? ma : ma - 32;
    int nh = (ng <= 15) ? ng : ng - 32;
    int am = mh < 0 ? -mh : mh;
    int an = nh < 0 ? -nh : nh;
    int l0 = am > an ? am : an;
    int lb = lq * 4;

    int isconj = (ma > 16);
    int mau = isconj ? (32 - ma) : ma;
    int ngu = isconj ? ((32 - ng) & 31) : ng;
    if (mau > 15) { mau = 0; ngu = 0; }   // ma==16: l0==16, values unused

    int tl[4];
#pragma unroll
    for (int j = 0; j < 4; j++) {
        int l = lb + j;
        tl[j] = LB[l] + (mh + l) * (2 * l + 1) + (nh + l);
    }
    float2 acc[4];
#pragma unroll
    for (int j = 0; j < 4; j++) acc[j] = make_float2(0.f, 0.f);

    const u32* xp = Xfb + (size_t)zi * 32 * 512 + mau * 32 + ngu;
    float sgn = isconj ? -1.f : 1.f;
#pragma unroll 2
    for (int bq = 0; bq < 8; bq++) {
        u32 p0 = xp[(size_t)(4 * bq + 0) * 512];
        u32 p1 = xp[(size_t)(4 * bq + 1) * 512];
        u32 p2 = xp[(size_t)(4 * bq + 2) * 512];
        u32 p3 = xp[(size_t)(4 * bq + 3) * 512];
        float vx0 = __uint_as_float(p0 << 16);
        float vy0 = sgn * __uint_as_float(p0 & 0xffff0000u);
        float vx1 = __uint_as_float(p1 << 16);
        float vy1 = sgn * __uint_as_float(p1 & 0xffff0000u);
        float vx2 = __uint_as_float(p2 << 16);
        float vy2 = sgn * __uint_as_float(p2 & 0xffff0000u);
        float vx3 = __uint_as_float(p3 << 16);
        float vy3 = sgn * __uint_as_float(p3 & 0xffff0000u);
        const float4* wq = (const float4*)(wfT + (size_t)bq * (LTOT * 4));
#pragma unroll
        for (int j = 0; j < 4; j++) {
            if (lb + j >= l0) {
                float4 w = wq[tl[j]];
                acc[j].x += w.x * vx0 + w.y * vx1 + w.z * vx2 + w.w * vx3;
                acc[j].y += w.x * vy0 + w.y * vy1 + w.z * vy2 + w.w * vy3;
            }
        }
    }
    int s_i  = i >> 4;
    int kl   = 2 * (i & 15);
    int joff = kl & 7;
    int Lhi  = (kl >> 3) << 4;
#pragma unroll
    for (int j = 0; j < 4; j++) {
        int l = lb + j;
        if (l >= l0) {
            int mi = mh + l, ni = nh + l;
            int s   = 2 * ni + s_i;
            int row = 4 * mi + z;
            u32 pack = pack2bf(acc[j].x, acc[j].y);
            size_t off = (size_t)8192 * l * l + (size_t)s * 4096
                       + ((row >> 4) << 9) + ((Lhi + (row & 15)) << 3) + joff;
            *(u32*)(Ab + off) = pack;
        }
    }
}

// ---------------------------------------------------------------------------
// MFMA GEMM, R16: K-split, two partial buffers, plain stores.
// 2048 blocks = sum_l 8*(2l+1), big l first: block = (l, n, oq, kh2).
// kh2 halves the k-range; each half writes a COMPLETE m x zo partial tile
// (m-loop independent of k) -> kh2=0 stores to zhT0, kh2=1 to zhT1; no
// memset, no atomics. XCD swizzle groups the 8 (oq,kh2) siblings (shared
// A-panel) onto one XCD. NO LDS, NO barriers; fragment-ordered yhb uint4
// B loads; per-lane perm+xor; 2-deep register pipeline; unconditional tail
// prefetch (OOB reads stay inside the 60MB workspace; values dead).
// ---------------------------------------------------------------------------
__global__ __launch_bounds__(256, 8) void k_gemm(const u16* __restrict__ Ab,
                                                 const u32* __restrict__ yhb,
                                                 float* __restrict__ zhT0,
                                                 float* __restrict__ zhT1) {
    int d = (int)blockIdx.x;
    int rem = ((d & 255) << 3) | (d >> 8);   // siblings -> same dispatch%8 -> same XCD
    int l, nl = 1;
    for (l = 15; l >= 0; l--) {
        nl = 2 * l + 1;
        int c = nl * 8;
        if (rem < c) break;
        rem -= c;
    }
    int kh2 = rem & 1;
    int oq  = (rem >> 1) & 3;
    int n   = rem >> 3;
    int base = LB[l];
    const u16* Ag = Ab + (size_t)8192 * l * l;
    int khalf = (nl + 1) >> 1;
    int s0    = kh2 ? 2 * khalf : 0;
    int s_end = kh2 ? 2 * nl    : 2 * khalf;
    float* zhT = kh2 ? zhT1 : zhT0;

    int tid = threadIdx.x, lane = tid & 63, w = tid >> 6;
    int cc = lane & 1;
    u32 sel = cc ? 0x01000302u : 0x03020100u;   // ror16 : identity
    u32 msk = cc ? 0u          : 0x80000000u;   // 0     : negate-hi

    const u32* Bb = yhb + (size_t)(base + n) * 2048 + (oq << 8) + ((lane >> 1) << 2);
    const u16* Aw = Ag + ((w << 10) | (lane << 3));

    floatx4 acc[2][2];
#pragma unroll
    for (int a = 0; a < 2; a++)
#pragma unroll
        for (int b = 0; b < 2; b++) acc[a][b] = (floatx4)0.f;

#define LOADB(s, q0, q1) { \
    const uint4* bp = (const uint4*)(Bb + (size_t)((s) >> 1) * nl * 2048 + (((s) & 1) << 10)); \
    q0 = bp[0]; q1 = bp[32]; }
#define LOADA(s, r0, r1) { \
    const u16* apx = Aw + (size_t)(s) * 4096; \
    r0 = *(const short8*)apx; r1 = *(const short8*)(apx + 512); }
#define MF(a, b, c) __builtin_amdgcn_mfma_f32_16x16x32_bf16(a, b, c, 0, 0, 0)

    uint4 eB0, eB1; short8 ea0, ea1;   // even-step raw
    uint4 oB0, oB1; short8 oa0, oa1;   // odd-step raw
    LOADA(s0, ea0, ea1);     LOADB(s0, eB0, eB1);
    LOADA(s0 + 1, oa0, oa1); LOADB(s0 + 1, oB0, oB1);

    for (int s = s0; s < s_end; s += 2) {
        // even step: transform (waits on its loads), refill regs, then MFMA
        short8 bf0 = btr4(eB0, sel, msk), bf1 = btr4(eB1, sel, msk);
        short8 af0 = ea0, af1 = ea1;
        LOADA(s + 2, ea0, ea1); LOADB(s + 2, eB0, eB1);
        acc[0][0] = MF(af0, bf0, acc[0][0]);  acc[1][0] = MF(af1, bf0, acc[1][0]);
        acc[0][1] = MF(af0, bf1, acc[0][1]);  acc[1][1] = MF(af1, bf1, acc[1][1]);
        // odd step
        short8 cf0 = btr4(oB0, sel, msk), cf1 = btr4(oB1, sel, msk);
        short8 ag0 = oa0, ag1 = oa1;
        LOADA(s + 3, oa0, oa1); LOADB(s + 3, oB0, oB1);
        acc[0][0] = MF(ag0, cf0, acc[0][0]);  acc[1][0] = MF(ag1, cf0, acc[1][0]);
        acc[0][1] = MF(ag0, cf1, acc[0][1]);  acc[1][1] = MF(ag1, cf1, acc[1][1]);
    }
#undef LOADB
#undef LOADA
#undef MF

    int q = lane >> 4, cn = lane & 15;
#pragma unroll
    for (int mt = 0; mt < 2; mt++) {
#pragma unroll
        for (int nt = 0; nt < 2; nt++) {
            int nu2 = (nt << 4) + cn;
            int o2  = (oq << 4) + (nu2 >> 1);
            int c2  = nu2 & 1;
#pragma unroll
            for (int r = 0; r < 4; r++) {
                int R = (w << 5) + (mt << 4) + (q << 2) + r;
                int m = R >> 2, z = R & 3;
                if (m < nl) {
                    int t  = base + m * nl + n;
                    int zo = (z << 6) + o2;
                    zhT[((size_t)zo * LTOT + t) * 2 + c2] = acc[mt][nt][r];
                }
            }
        }
    }
}

// ---------------------------------------------------------------------------
// Inverse, 4 betas per block. R14: packed-fp32 complex math throughout.
// gather: v_pk_fma broadcast MACs; pass 1: register twiddle rotation chains,
// zero twiddle LDS; pass 2: 135->15 LDS ops/task via chains + symmetries.
// Grid: 2048 = (bq 8) x (zo 256); 256 thr; ~17.7KB LDS.
// ---------------------------------------------------------------------------
__global__ __launch_bounds__(256, 8) void k_inv2(const float2* __restrict__ zhT,
                                                 const float* __restrict__ wiT,
                                                 const float* __restrict__ bias,
                                                 float* __restrict__ out) {
    __shared__ __align__(16) f32x2 Pb[4 * 544];  // plane p at p*544, rows stride 34
    __shared__ f32x2 Wf[32];                     // (cos, sin) 2pi i/32
    int tid = threadIdx.x;
    int zo = blockIdx.x & 255;
    int bq = blockIdx.x >> 8;
    int b0 = bq * 4;
    if (tid < 32) {
        float sv, cv;
        sincosf(6.28318530717958647692f * (float)tid / 32.0f, &sv, &cv);
        f32x2 wv; wv.x = cv; wv.y = sv;
        Wf[tid] = wv;
    }
    // ---- gather: thread = (ng 32, rq 8); 2 ma-rows; 4 betas share each zv
    {
        int ng = tid & 31, rq = tid >> 5;
        int nh = (ng <= 15) ? ng : ng - 32;
        int an = nh < 0 ? -nh : nh;
        const f32x2* zr = (const f32x2*)zhT + (size_t)zo * LTOT;
        const f32x2* wp = (const f32x2*)wiT + (size_t)bq * (LTOT * 2);
#pragma unroll
        for (int mr = 0; mr < 2; mr++) {
            int ma = rq + 8 * mr;
            int l0 = ma > an ? ma : an;
            f32x2 a0 = (f32x2)0.f, a1 = a0, a2 = a0, a3 = a0;
#pragma unroll 4
            for (int l = 0; l < 16; l++) {
                if (l >= l0) {
                    int t = LB[l] + (ma + l) * (2 * l + 1) + (nh + l);
                    f32x2 zv = zr[t];
                    f32x2 w01 = wp[2 * t], w23 = wp[2 * t + 1];
                    a0 = fma_bl(w01, zv, a0);
                    a1 = fma_bh(w01, zv, a1);
                    a2 = fma_bl(w23, zv, a2);
                    a3 = fma_bh(w23, zv, a3);
                }
            }
            int po = ma * 34 + ng;
            Pb[po]            = a0;
            Pb[544 + po]      = a1;
            Pb[2 * 544 + po]  = a2;
            Pb[3 * 544 + po]  = a3;
        }
    }
    __syncthreads();
    // ---- pass 1 (ng -> g): 64 rows x 8 q = 512 tasks over 2 rounds.
#pragma unroll
    for (int it = 0; it < 2; it++) {
        int task = tid + it * 256;
        int rowid = task >> 3, q = task & 7;
        f32x2* prow = &Pb[(rowid >> 4) * 544 + (rowid & 15) * 34];
        const floatx4* prow4 = (const floatx4*)prow;
        floatx4 eo0 = prow4[0];
        f32x2 Ep; Ep.x = eo0.x; Ep.y = eo0.y;
        f32x2 Op; Op.x = eo0.z; Op.y = eo0.w;
        f32x2 En = (f32x2)0.f, On = (f32x2)0.f;
        f32x2 r = Wf[2 * q];
        f32x2 t = r;
#pragma unroll
        for (int h = 1; h < 16; h++) {
            floatx4 eo = prow4[h];
            f32x2 e; e.x = eo.x; e.y = eo.y;
            f32x2 o; o.x = eo.z; o.y = eo.w;
            if (h & 1) { En = cfma(e, t, En); On = cfma(o, t, On); }
            else       { Ep = cfma(e, t, Ep); Op = cfma(o, t, Op); }
            if (h < 15) t = cmulp(t, r);
        }
        f32x2 E0 = Ep + En, E1 = Ep - En;
        f32x2 O0 = Op + On, O1 = Op - On;
        f32x2 wq = Wf[q];
        f32x2 w0 = cmulp(O0, wq);
        f32x2 u1 = cmulp(O1, wq);
        f32x2 w1; w1.x = -u1.y; w1.y = u1.x;     // i * u1  (W^{q+8} = i W^q)
        prow[q]      = E0 + w0;
        prow[q + 16] = E0 - w0;
        prow[q + 8]  = E1 + w1;
        prow[q + 24] = E1 - w1;
    }
    __syncthreads();
    // ---- pass 2 (ma -> a): tasks (p, qa, g) x4 rounds; direct store + bias
    float bv = bias[zo & 63];
#pragma unroll
    for (int it = 0; it < 4; it++) {
        int task = tid + it * 256;
        int p = task >> 8, rr = task & 255;
        int qa = rr >> 5, g = rr & 31;
        const f32x2* pc = &Pb[p * 544];
        f32x2 r = Wf[2 * qa];
        f32x2 u = Wf[qa];
        f32x2 Uee = (f32x2)0.f, Ueo = Uee, Ve = Uee, Vo = Uee;
        f32x2 c0 = pc[g];
        {   // j = 0: odd column only
            f32x2 c1 = pc[34 + g];
            Ve = cfma(c1, u, Ve);
        }
        f32x2 t = r;
        u = cmulp(u, r);
#pragma unroll
        for (int j = 1; j < 8; j++) {
            f32x2 ce = pc[(2 * j) * 34 + g];
            f32x2 co = pc[(2 * j + 1) * 34 + g];
            if (j & 1) { Ueo = cfma(ce, t, Ueo); Vo = cfma(co, u, Vo); }
            else       { Uee = cfma(ce, t, Uee); Ve = cfma(co, u, Ve); }
            if (j < 7) { t = cmulp(t, r); u = cmulp(u, r); }
        }
        float EaA = c0.x + 2.f * (Uee.x + Ueo.x);
        float EaB = c0.x + 2.f * (Uee.x - Ueo.x);
        float OaA = 2.f * (Ve.x + Vo.x);
        float OaB = -2.f * (Ve.y - Vo.y);
        float* dst = out + (size_t)zo * 32768 + (size_t)(b0 + p) * 1024;
        constexpr float sc = 1.f / 1024.f;
        dst[qa * 32 + g]         = (EaA + OaA) * sc + bv;
        dst[(qa + 16) * 32 + g]  = (EaA - OaA) * sc + bv;
        dst[(qa + 8) * 32 + g]   = (EaB + OaB) * sc + bv;
        dst[(qa + 24) * 32 + g]  = (EaB - OaB) * sc + bv;
    }
}

// ---------------------------------------------------------------------------
extern "C" void kernel_launch(void* const* d_in, const int* in_sizes, int n_in,
                              void* d_out, int out_size, void* d_ws, size_t ws_size,
                              hipStream_t stream) {
    const float* x    = (const float*)d_in[0];
    const float* ker  = (const float*)d_in[1];
    const float* bias = (const float*)d_in[2];
    const float* wf   = (const float*)d_in[3];
    const float* wi   = (const float*)d_in[4];
    const float* Dre  = (const float*)d_in[5];
    const float* Dim  = (const float*)d_in[6];
    float* out = (float*)d_out;

    // layout: yhb 44.7MB | Ab 4.2MB | zh_T 11.2MB.
    // Xfb (8.4MB) + wfT (698KB, at zhT+8.39MB) alias zh_T: both dead once
    // k_gemm writes zhT. wiT (698KB) aliases yhb base: written after k_gemm
    // (yhb dead), read by k_inv2. zhT1 = d_out (scratch until k_inv2; out is
    // fully overwritten by k_inv2).
    char* ws = (char*)d_ws;
    u32*    yhb = (u32*)ws;
    u16*    Ab  = (u16*)(ws + 44695552);
    float*  zhT = (float*)(ws + 44695552 + 4194304);
    u32*    Xfb = (u32*)zhT;                                    // disjoint lifetime vs zh_T
    float*  wfT = (float*)(ws + 44695552 + 4194304 + 8388608);  // zhT tail, pre-gemm
    float*  wiT = (float*)ws;                                   // yhb region, post-gemm
    float*  zhT1 = out;                                         // scratch until k_inv2

    hipLaunchKernelGGL(k_fft_fwd, dim3(4096),  dim3(512), 0, stream, x, Xfb);
    hipLaunchKernelGGL(k_wtr,     dim3(22, 8), dim3(256), 0, stream, wf, wfT);
    hipLaunchKernelGGL(k_prep_B,  dim3(682),   dim3(256), 0, stream, Dre, Dim, ker, yhb);
    hipLaunchKernelGGL(k_beta_A,  dim3(2048),  dim3(256), 0, stream, Xfb, wfT, Ab);
    hipLaunchKernelGGL(k_gemm,    dim3(2048),  dim3(256), 0, stream, Ab, yhb, zhT, zhT1);
    hipLaunchKernelGGL(k_red,     dim3(2728),  dim3(256), 0, stream,
                       (float4*)zhT, (const float4*)zhT1);
    hipLaunchKernelGGL(k_wtr,     dim3(22, 8), dim3(256), 0, stream, wi, wiT);
    hipLaunchKernelGGL(k_inv2,    dim3(2048),  dim3(256), 0, stream,
                       (const float2*)zhT, wiT, bias, out);
}

// Round 10
// 202.325 us; speedup vs baseline: 1.6220x; 1.1688x over previous
//
#include <hip/hip_runtime.h>
#include <math.h>

// ---------------------------------------------------------------------------
// SO3 convolution. bf16 MFMA GEMM (complex-as-real); Hermitian-half FFT/IFFT.
// Pipeline: k_fft_fwd -> k_wtr(wf) -> k_prep_B -> k_beta_A
//           -> k_gemm (MFMA) -> k_wtr(wi) -> k_inv2
// R8 lesson: fusing fft+prep spilled -- keep kernels separate.
// R9: wfT/wiT [bq][t][4] transposes -- big win in k_beta_A.
// R10: k_inv2 streamed FFT passes (VGPR 92->64), 8 blocks/CU -- 68->~40us.
// R11 NEUTRAL: depth-1 prefetch didn't move k_gemm (latency-bound, no TLP).
// R12: yhb in MFMA-fragment order; k_gemm no-LDS no-barrier -- ~49us.
// R13: o-quarter split, 1024 blocks -- Occ 13->27%, -12% time only.
// R14: k_inv2 packed-fp32 complex math + register twiddle chains -- <42us.
// R15 DISASTER (155us): scattered unsafeAtomicAdd = atomic-pipe ceiling.
// R16 REGRESSION (70us): two partial buffers = write-allocate RMW at HBM.
// Scattered-store reductions are poison in ANY form.
// R17 BROKEN: distance-4 pipeline had a DOUBLE-COUNT tail: S=4l+2, peel(2)
// + l loop iters x4 covers ALL steps; the appended "final 2 steps" block
// re-added pair1's prefetched garbage (steps S..S+1) -> absmax 389.
// R18: R17 with the bogus tail deleted. Step coverage verified per l.
// Workspace: yhb 44.7MB | Ab 4.2MB | zh_T 11.2MB.
//   Xfb (8.4MB) + wfT (698KB) alias zh_T (lifetime fft->gemm, disjoint).
//   wiT (698KB) aliases yhb base (written after gemm, read by inv2).
// ---------------------------------------------------------------------------

typedef unsigned short u16;
typedef unsigned int   u32;
typedef __attribute__((ext_vector_type(8))) short  short8;   // 8 bf16
typedef __attribute__((ext_vector_type(4))) float  floatx4;
typedef __attribute__((ext_vector_type(2))) float  f32x2;

constexpr int LTOT = 5456;

constexpr int LB[17] = {0,1,10,35,84,165,286,455,680,969,
                        1330,1771,2300,2925,3654,4495,5456};

__device__ inline u16 f2bf(float f) {
    u32 u = __float_as_uint(f);
    u += 0x7fff + ((u >> 16) & 1);
    return (u16)(u >> 16);
}
__device__ inline u32 pack2bf(float re, float im) {
    return (u32)f2bf(re) | ((u32)f2bf(im) << 16);
}

// cc-dependent complex pack transform: cc=0 -> (re,-im) == b ^ 0x80000000;
// cc=1 -> (im,re) == ror16(b). Done as per-lane-constant perm + xor.
__device__ inline short8 btr4(uint4 q, u32 sel, u32 msk) {
    uint4 t;
    t.x = __builtin_amdgcn_perm(q.x, q.x, sel) ^ msk;
    t.y = __builtin_amdgcn_perm(q.y, q.y, sel) ^ msk;
    t.z = __builtin_amdgcn_perm(q.z, q.z, sel) ^ msk;
    t.w = __builtin_amdgcn_perm(q.w, q.w, sel) ^ msk;
    return *(short8*)&t;
}

// ---- packed-fp32 complex helpers (VOP3P). acc/result = (re, im) pairs. ----
__device__ __forceinline__ f32x2 cfma(f32x2 e, f32x2 t, f32x2 acc) {
    asm("v_pk_fma_f32 %0, %1, %2, %0 op_sel:[0,0,0] op_sel_hi:[0,1,1]\n\t"
        "v_pk_fma_f32 %0, %1, %2, %0 op_sel:[1,1,0] op_sel_hi:[1,0,1] neg_lo:[0,1,0]"
        : "+v"(acc) : "v"(e), "v"(t));
    return acc;
}
__device__ __forceinline__ f32x2 cmulp(f32x2 t, f32x2 r) {
    f32x2 d;
    asm("v_pk_mul_f32 %0, %1, %2 op_sel:[0,0] op_sel_hi:[0,1]\n\t"
        "v_pk_fma_f32 %0, %1, %2, %0 op_sel:[1,1,0] op_sel_hi:[1,0,1] neg_lo:[0,1,0]"
        : "=&v"(d) : "v"(t), "v"(r));
    return d;
}
__device__ __forceinline__ f32x2 fma_bl(f32x2 w2, f32x2 v, f32x2 acc) {
    asm("v_pk_fma_f32 %0, %1, %2, %0 op_sel:[0,0,0] op_sel_hi:[0,1,1]"
        : "+v"(acc) : "v"(w2), "v"(v));
    return acc;
}
__device__ __forceinline__ f32x2 fma_bh(f32x2 w2, f32x2 v, f32x2 acc) {
    asm("v_pk_fma_f32 %0, %1, %2, %0 op_sel:[1,0,0] op_sel_hi:[1,1,1]"
        : "+v"(acc) : "v"(w2), "v"(v));
    return acc;
}

// ---------------------------------------------------------------------------
// Wigner-table transpose: w[32][LTOT] -> wT[bq(8)][t][4] so a 4-beta group is
// one float4. Grid (22, 8) x 256.
// ---------------------------------------------------------------------------
__global__ __launch_bounds__(256) void k_wtr(const float* __restrict__ w,
                                             float* __restrict__ wT) {
    int t  = blockIdx.x * 256 + threadIdx.x;
    int bq = blockIdx.y;
    if (t < LTOT) {
        float4 v;
        v.x = w[(size_t)(bq * 4 + 0) * LTOT + t];
        v.y = w[(size_t)(bq * 4 + 1) * LTOT + t];
        v.z = w[(size_t)(bq * 4 + 2) * LTOT + t];
        v.w = w[(size_t)(bq * 4 + 3) * LTOT + t];
        *(float4*)(wT + ((size_t)bq * LTOT + t) * 4) = v;
    }
}

// ---------------------------------------------------------------------------
// Forward FFT2 (e^{-i}), radix-2 both passes, 512 threads, one task each.
// Stores ONLY Hermitian-half rows ma 0..15, bf16-packed.
// x: [z][i][b][a][g].   Xfb: [zi*32+b][ma(0..15)][ng] packed bf16 pairs.
// ---------------------------------------------------------------------------
__global__ __launch_bounds__(512) void k_fft_fwd(const float* __restrict__ x,
                                                 u32* __restrict__ Xfb) {
    __shared__ float xs[1056];               // [a][g] stride 33
    __shared__ float Gre[1056], Gim[1056];   // [a][k] stride 33
    __shared__ float Wc[32], Ws[32];
    int tid = threadIdx.x;
    if (tid < 32) {
        float sv, cv;
        sincosf(6.28318530717958647692f * (float)tid / 32.0f, &sv, &cv);
        Wc[tid] = cv; Ws[tid] = sv;
    }
    const float* src = x + (size_t)blockIdx.x * 1024;
    for (int e = tid; e < 1024; e += 512) xs[(e >> 5) * 33 + (e & 31)] = src[e];
    __syncthreads();
    // pass 1 over g (real input), radix-2: task = (a, k in 0..15)
    {
        int a = tid >> 4, k = tid & 15;
        const float* row = &xs[a * 33];
        float Er = 0.f, Ei = 0.f, Or = 0.f, Oi = 0.f;
#pragma unroll
        for (int h = 0; h < 16; h++) {
            int idx = (2 * h * k) & 31;
            float c = Wc[idx], s = Ws[idx];
            float xe = row[2 * h], xo = row[2 * h + 1];
            Er += xe * c;  Ei -= xe * s;
            Or += xo * c;  Oi -= xo * s;
        }
        float WOr = Or * Wc[k] + Oi * Ws[k];
        float WOi = Oi * Wc[k] - Or * Ws[k];
        Gre[a * 33 + k]      = Er + WOr;
        Gim[a * 33 + k]      = Ei + WOi;
        Gre[a * 33 + k + 16] = Er - WOr;
        Gim[a * 33 + k + 16] = Ei - WOi;
    }
    __syncthreads();
    // pass 2 over a, radix-2 combine; store only row ma (0..15)
    {
        u32* dst = Xfb + (size_t)blockIdx.x * 512;
        int ng = tid & 31, ma = tid >> 5;
        float Er = 0.f, Ei = 0.f, Or = 0.f, Oi = 0.f;
#pragma unroll
        for (int h = 0; h < 16; h++) {
            int idx = (2 * h * ma) & 31;
            float c = Wc[idx], s = Ws[idx];
            float er = Gre[(2 * h) * 33 + ng],      ei = Gim[(2 * h) * 33 + ng];
            float orr = Gre[(2 * h + 1) * 33 + ng], oi = Gim[(2 * h + 1) * 33 + ng];
            Er += er * c + ei * s;   Ei += ei * c - er * s;
            Or += orr * c + oi * s;  Oi += oi * c - orr * s;
        }
        float WOr = Or * Wc[ma] + Oi * Ws[ma];
        float WOi = Oi * Wc[ma] - Or * Ws[ma];
        dst[ma * 32 + ng] = pack2bf(Er + WOr, Ei + WOi);
    }
}

// ---------------------------------------------------------------------------
// Build compact bf16 yh in MFMA-FRAGMENT ORDER (R12):
// io = (i,o): i = ih*16+kh*4+j, o = oh*32+nt*8+ph
// nio = ih*1024 + oh*512 + nt*128 + kh*32 + ph*4 + j
// so k_gemm's lane fragment (4 words j=0..3) is one contiguous uint4.
// ---------------------------------------------------------------------------
__global__ __launch_bounds__(256) void k_prep_B(const float* __restrict__ Dre,
                                                const float* __restrict__ Dim,
                                                const float* __restrict__ ker,
                                                u32* __restrict__ yhb) {
    __shared__ float Ds[8][24];
    int t0  = blockIdx.x * 8;
    int tid = threadIdx.x;
    if (tid < 192) {
        int rr = tid / 24, jj = tid - rr * 24;
        Ds[rr][jj] = (jj < 12) ? Dre[(t0 + rr) * 12 + jj] : Dim[(t0 + rr) * 12 + jj - 12];
    }
    __syncthreads();
    for (int rep = 0; rep < 8; rep++) {
        int io = rep * 256 + tid;
        int i  = io >> 6, o = io & 63;
        int nio = ((i >> 4) << 10) + ((o >> 5) << 9) + (((o >> 3) & 3) << 7)
                + (((i >> 2) & 3) << 5) + ((o & 7) << 2) + (i & 3);
        const float4* kp = (const float4*)(ker + io * 12);
        float4 ka = kp[0], kb = kp[1], kc = kp[2];
        float kv[12] = {ka.x, ka.y, ka.z, ka.w, kb.x, kb.y, kb.z, kb.w,
                        kc.x, kc.y, kc.z, kc.w};
#pragma unroll
        for (int rr = 0; rr < 8; rr++) {
            float sr = 0.f, si = 0.f;
#pragma unroll
            for (int j = 0; j < 12; j++) {
                sr += Ds[rr][j]      * kv[j];
                si += Ds[rr][12 + j] * kv[j];
            }
            yhb[(size_t)(t0 + rr) * 2048 + nio] = pack2bf(sr, si);
        }
    }
}

// ---------------------------------------------------------------------------
// Fused beta-contraction + bf16 A-fragment pack. Xfb is Hermitian-half:
// rows ma 0..15 stored; ma>=17 read as conj(Xf[32-ma][(32-ng)&31]).
// Grid: (ma 32) x (zig 64) = 2048 blocks; thread = (zil 2, lq 4, ng 32).
// R9: b-loop grouped in beta-quads; wfT[bq][t][4] gives one float4 per
// (bq, l) instead of 4 scalar strided loads.
// ---------------------------------------------------------------------------
__global__ __launch_bounds__(256) void k_beta_A(const u32* __restrict__ Xfb,
                                                const float* __restrict__ wfT,
                                                u16* __restrict__ Ab) {
    int ma  = blockIdx.x >> 6;
    int zig = blockIdx.x & 63;
    int tid = threadIdx.x;
    int ng  = tid & 31;
    int lq  = (tid >> 5) & 3;
    int zil = tid >> 7;
    int zi  = zig * 2 + zil;
    int z = zi >> 5, i = zi & 31;
    int mh = (ma <= 15) ? ma : ma - 32;
    int nh = (ng <= 15) ? ng : ng - 32;
    int am = mh < 0 ? -mh : mh;
    int an = nh < 0 ? -nh : nh;
    int l0 = am > an ? am : an;
    int lb = lq * 4;

    int isconj = (ma > 16);
    int mau = isconj ? (32 - ma) : ma;
    int ngu = isconj ? ((32 - ng) & 31) : ng;
    if (mau > 15) { mau = 0; ngu = 0; }   // ma==16: l0==16, values unused

    int tl[4];
#pragma unroll
    for (int j = 0; j < 4; j++) {
        int l = lb + j;
        tl[j] = LB[l] + (mh + l) * (2 * l + 1) + (nh + l);
    }
    float2 acc[4];
#pragma unroll
    for (int j = 0; j < 4; j++) acc[j] = make_float2(0.f, 0.f);

    const u32* xp = Xfb + (size_t)zi * 32 * 512 + mau * 32 + ngu;
    float sgn = isconj ? -1.f : 1.f;
#pragma unroll 2
    for (int bq = 0; bq < 8; bq++) {
        u32 p0 = xp[(size_t)(4 * bq + 0) * 512];
        u32 p1 = xp[(size_t)(4 * bq + 1) * 512];
        u32 p2 = xp[(size_t)(4 * bq + 2) * 512];
        u32 p3 = xp[(size_t)(4 * bq + 3) * 512];
        float vx0 = __uint_as_float(p0 << 16);
        float vy0 = sgn * __uint_as_float(p0 & 0xffff0000u);
        float vx1 = __uint_as_float(p1 << 16);
        float vy1 = sgn * __uint_as_float(p1 & 0xffff0000u);
        float vx2 = __uint_as_float(p2 << 16);
        float vy2 = sgn * __uint_as_float(p2 & 0xffff0000u);
        float vx3 = __uint_as_float(p3 << 16);
        float vy3 = sgn * __uint_as_float(p3 & 0xffff0000u);
        const float4* wq = (const float4*)(wfT + (size_t)bq * (LTOT * 4));
#pragma unroll
        for (int j = 0; j < 4; j++) {
            if (lb + j >= l0) {
                float4 w = wq[tl[j]];
                acc[j].x += w.x * vx0 + w.y * vx1 + w.z * vx2 + w.w * vx3;
                acc[j].y += w.x * vy0 + w.y * vy1 + w.z * vy2 + w.w * vy3;
            }
        }
    }
    int s_i  = i >> 4;
    int kl   = 2 * (i & 15);
    int joff = kl & 7;
    int Lhi  = (kl >> 3) << 4;
#pragma unroll
    for (int j = 0; j < 4; j++) {
        int l = lb + j;
        if (l >= l0) {
            int mi = mh + l, ni = nh + l;
            int s   = 2 * ni + s_i;
            int row = 4 * mi + z;
            u32 pack = pack2bf(acc[j].x, acc[j].y);
            size_t off = (size_t)8192 * l * l + (size_t)s * 4096
                       + ((row >> 4) << 9) + ((Lhi + (row & 15)) << 3) + joff;
            *(u32*)(Ab + off) = pack;
        }
    }
}

// ---------------------------------------------------------------------------
// MFMA GEMM, R18: o-quarter split + DISTANCE-4 register pipeline (R17 fixed).
// 1024 blocks = sum_l 4*(2l+1), big l first: block = (l, n, oq).
// Two named buffer pairs: pair0 = steps s,s+1; pair1 = s+2,s+3; each
// refilled 4 steps ahead -> 2x latency cover vs R14's distance-2.
// S = 4l+2: peel(2 steps) + l loop iters x 4 covers ALL steps exactly --
// NO tail block (R17's tail double-added prefetched garbage).
// NO LDS, NO barriers; fragment-ordered yhb uint4 B loads; per-lane
// perm+xor; unconditional tail prefetch (OOB <=0.5MB past region ends,
// inside 60MB ws; values dead).
// Output transposed: zh_T[zo][t] (float pairs), plain stores (single buffer;
// R15/R16: scattered-store reductions are poison).
// ---------------------------------------------------------------------------
__global__ __launch_bounds__(256) void k_gemm(const u16* __restrict__ Ab,
                                              const u32* __restrict__ yhb,
                                              float* __restrict__ zhT) {
    int rem = blockIdx.x, l, nl = 1;
    for (l = 15; l >= 0; l--) {
        nl = 2 * l + 1;
        int c = nl * 4;
        if (rem < c) break;
        rem -= c;
    }
    int n  = rem >> 2;
    int oq = rem & 3;
    int base = LB[l];
    const u16* Ag = Ab + (size_t)8192 * l * l;
    int S = 2 * nl;

    int tid = threadIdx.x, lane = tid & 63, w = tid >> 6;
    int cc = lane & 1;
    u32 sel = cc ? 0x01000302u : 0x03020100u;   // ror16 : identity
    u32 msk = cc ? 0u          : 0x80000000u;   // 0     : negate-hi

    const u32* Bb = yhb + (size_t)(base + n) * 2048 + (oq << 8) + ((lane >> 1) << 2);
    const u16* Aw = Ag + ((w << 10) | (lane << 3));

    floatx4 acc[2][2];
#pragma unroll
    for (int a = 0; a < 2; a++)
#pragma unroll
        for (int b = 0; b < 2; b++) acc[a][b] = (floatx4)0.f;

#define LOADB(s, q0, q1) { \
    const uint4* bp = (const uint4*)(Bb + (size_t)((s) >> 1) * nl * 2048 + (((s) & 1) << 10)); \
    q0 = bp[0]; q1 = bp[32]; }
#define LOADA(s, r0, r1) { \
    const u16* apx = Aw + (size_t)(s) * 4096; \
    r0 = *(const short8*)apx; r1 = *(const short8*)(apx + 512); }
#define MF(a, b, c) __builtin_amdgcn_mfma_f32_16x16x32_bf16(a, b, c, 0, 0, 0)
// compute 2 steps from a pair's regs, then refill that pair from step snew
#define COMP2REFILL(Bx0, Bx1, Ax0, Ax1, By0, By1, Ay0, Ay1, snew) { \
    short8 bf0 = btr4(Bx0, sel, msk), bf1 = btr4(Bx1, sel, msk); \
    short8 af0 = Ax0, af1 = Ax1; \
    short8 cf0 = btr4(By0, sel, msk), cf1 = btr4(By1, sel, msk); \
    short8 ag0 = Ay0, ag1 = Ay1; \
    LOADA(snew, Ax0, Ax1); LOADB(snew, Bx0, Bx1); \
    LOADA((snew) + 1, Ay0, Ay1); LOADB((snew) + 1, By0, By1); \
    acc[0][0] = MF(af0, bf0, acc[0][0]);  acc[1][0] = MF(af1, bf0, acc[1][0]); \
    acc[0][1] = MF(af0, bf1, acc[0][1]);  acc[1][1] = MF(af1, bf1, acc[1][1]); \
    acc[0][0] = MF(ag0, cf0, acc[0][0]);  acc[1][0] = MF(ag1, cf0, acc[1][0]); \
    acc[0][1] = MF(ag0, cf1, acc[0][1]);  acc[1][1] = MF(ag1, cf1, acc[1][1]); }

    // pair0 = steps s, s+1; pair1 = steps s+2, s+3
    uint4 p0B0, p0B1, p0C0, p0C1; short8 p0a0, p0a1, p0c0, p0c1;
    uint4 p1B0, p1B1, p1C0, p1C1; short8 p1a0, p1a1, p1c0, p1c1;
    LOADA(0, p0a0, p0a1); LOADB(0, p0B0, p0B1);
    LOADA(1, p0c0, p0c1); LOADB(1, p0C0, p0C1);
    LOADA(2, p1a0, p1a1); LOADB(2, p1B0, p1B1);
    LOADA(3, p1c0, p1c1); LOADB(3, p1C0, p1C1);

    // peel: steps 0,1. Then l iterations of 4 steps = 4l -> total 4l+2 = S.
    COMP2REFILL(p0B0, p0B1, p0a0, p0a1, p0C0, p0C1, p0c0, p0c1, 4);
    for (int s = 2; s + 2 < S; s += 4) {
        COMP2REFILL(p1B0, p1B1, p1a0, p1a1, p1C0, p1C1, p1c0, p1c1, s + 4);
        COMP2REFILL(p0B0, p0B1, p0a0, p0a1, p0C0, p0C1, p0c0, p0c1, s + 6);
    }
    // no tail: loop covers through step S-1 (R17's tail was a double-count)
#undef COMP2REFILL
#undef LOADB
#undef LOADA
#undef MF

    int q = lane >> 4, cn = lane & 15;
#pragma unroll
    for (int mt = 0; mt < 2; mt++) {
#pragma unroll
        for (int nt = 0; nt < 2; nt++) {
            int nu2 = (nt << 4) + cn;
            int o2  = (oq << 4) + (nu2 >> 1);
            int c2  = nu2 & 1;
#pragma unroll
            for (int r = 0; r < 4; r++) {
                int R = (w << 5) + (mt << 4) + (q << 2) + r;
                int m = R >> 2, z = R & 3;
                if (m < nl) {
                    int t  = base + m * nl + n;
                    int zo = (z << 6) + o2;
                    zhT[((size_t)zo * LTOT + t) * 2 + c2] = acc[mt][nt][r];
                }
            }
        }
    }
}

// ---------------------------------------------------------------------------
// Inverse, 4 betas per block. R14: packed-fp32 complex math throughout.
// gather: v_pk_fma broadcast MACs; pass 1: register twiddle rotation chains,
// zero twiddle LDS; pass 2: 135->15 LDS ops/task via chains + symmetries.
// Grid: 2048 = (bq 8) x (zo 256); 256 thr; ~17.7KB LDS.
// ---------------------------------------------------------------------------
__global__ __launch_bounds__(256, 8) void k_inv2(const float2* __restrict__ zhT,
                                                 const float* __restrict__ wiT,
                                                 const float* __restrict__ bias,
                                                 float* __restrict__ out) {
    __shared__ __align__(16) f32x2 Pb[4 * 544];  // plane p at p*544, rows stride 34
    __shared__ f32x2 Wf[32];                     // (cos, sin) 2pi i/32
    int tid = threadIdx.x;
    int zo = blockIdx.x & 255;
    int bq = blockIdx.x >> 8;
    int b0 = bq * 4;
    if (tid < 32) {
        float sv, cv;
        sincosf(6.28318530717958647692f * (float)tid / 32.0f, &sv, &cv);
        f32x2 wv; wv.x = cv; wv.y = sv;
        Wf[tid] = wv;
    }
    // ---- gather: thread = (ng 32, rq 8); 2 ma-rows; 4 betas share each zv
    {
        int ng = tid & 31, rq = tid >> 5;
        int nh = (ng <= 15) ? ng : ng - 32;
        int an = nh < 0 ? -nh : nh;
        const f32x2* zr = (const f32x2*)zhT + (size_t)zo * LTOT;
        const f32x2* wp = (const f32x2*)wiT + (size_t)bq * (LTOT * 2);
#pragma unroll
        for (int mr = 0; mr < 2; mr++) {
            int ma = rq + 8 * mr;
            int l0 = ma > an ? ma : an;
            f32x2 a0 = (f32x2)0.f, a1 = a0, a2 = a0, a3 = a0;
#pragma unroll 4
            for (int l = 0; l < 16; l++) {
                if (l >= l0) {
                    int t = LB[l] + (ma + l) * (2 * l + 1) + (nh + l);
                    f32x2 zv = zr[t];
                    f32x2 w01 = wp[2 * t], w23 = wp[2 * t + 1];
                    a0 = fma_bl(w01, zv, a0);
                    a1 = fma_bh(w01, zv, a1);
                    a2 = fma_bl(w23, zv, a2);
                    a3 = fma_bh(w23, zv, a3);
                }
            }
            int po = ma * 34 + ng;
            Pb[po]            = a0;
            Pb[544 + po]      = a1;
            Pb[2 * 544 + po]  = a2;
            Pb[3 * 544 + po]  = a3;
        }
    }
    __syncthreads();
    // ---- pass 1 (ng -> g): 64 rows x 8 q = 512 tasks over 2 rounds.
#pragma unroll
    for (int it = 0; it < 2; it++) {
        int task = tid + it * 256;
        int rowid = task >> 3, q = task & 7;
        f32x2* prow = &Pb[(rowid >> 4) * 544 + (rowid & 15) * 34];
        const floatx4* prow4 = (const floatx4*)prow;
        floatx4 eo0 = prow4[0];
        f32x2 Ep; Ep.x = eo0.x; Ep.y = eo0.y;
        f32x2 Op; Op.x = eo0.z; Op.y = eo0.w;
        f32x2 En = (f32x2)0.f, On = (f32x2)0.f;
        f32x2 r = Wf[2 * q];
        f32x2 t = r;
#pragma unroll
        for (int h = 1; h < 16; h++) {
            floatx4 eo = prow4[h];
            f32x2 e; e.x = eo.x; e.y = eo.y;
            f32x2 o; o.x = eo.z; o.y = eo.w;
            if (h & 1) { En = cfma(e, t, En); On = cfma(o, t, On); }
            else       { Ep = cfma(e, t, Ep); Op = cfma(o, t, Op); }
            if (h < 15) t = cmulp(t, r);
        }
        f32x2 E0 = Ep + En, E1 = Ep - En;
        f32x2 O0 = Op + On, O1 = Op - On;
        f32x2 wq = Wf[q];
        f32x2 w0 = cmulp(O0, wq);
        f32x2 u1 = cmulp(O1, wq);
        f32x2 w1; w1.x = -u1.y; w1.y = u1.x;     // i * u1  (W^{q+8} = i W^q)
        prow[q]      = E0 + w0;
        prow[q + 16] = E0 - w0;
        prow[q + 8]  = E1 + w1;
        prow[q + 24] = E1 - w1;
    }
    __syncthreads();
    // ---- pass 2 (ma -> a): tasks (p, qa, g) x4 rounds; direct store + bias
    float bv = bias[zo & 63];
#pragma unroll
    for (int it = 0; it < 4; it++) {
        int task = tid + it * 256;
        int p = task >> 8, rr = task & 255;
        int qa = rr >> 5, g = rr & 31;
        const f32x2* pc = &Pb[p * 544];
        f32x2 r = Wf[2 * qa];
        f32x2 u = Wf[qa];
        f32x2 Uee = (f32x2)0.f, Ueo = Uee, Ve = Uee, Vo = Uee;
        f32x2 c0 = pc[g];
        {   // j = 0: odd column only
            f32x2 c1 = pc[34 + g];
            Ve = cfma(c1, u, Ve);
        }
        f32x2 t = r;
        u = cmulp(u, r);
#pragma unroll
        for (int j = 1; j < 8; j++) {
            f32x2 ce = pc[(2 * j) * 34 + g];
            f32x2 co = pc[(2 * j + 1) * 34 + g];
            if (j & 1) { Ueo = cfma(ce, t, Ueo); Vo = cfma(co, u, Vo); }
            else       { Uee = cfma(ce, t, Uee); Ve = cfma(co, u, Ve); }
            if (j < 7) { t = cmulp(t, r); u = cmulp(u, r); }
        }
        float EaA = c0.x + 2.f * (Uee.x + Ueo.x);
        float EaB = c0.x + 2.f * (Uee.x - Ueo.x);
        float OaA = 2.f * (Ve.x + Vo.x);
        float OaB = -2.f * (Ve.y - Vo.y);
        float* dst = out + (size_t)zo * 32768 + (size_t)(b0 + p) * 1024;
        constexpr float sc = 1.f / 1024.f;
        dst[qa * 32 + g]         = (EaA + OaA) * sc + bv;
        dst[(qa + 16) * 32 + g]  = (EaA - OaA) * sc + bv;
        dst[(qa + 8) * 32 + g]   = (EaB + OaB) * sc + bv;
        dst[(qa + 24) * 32 + g]  = (EaB - OaB) * sc + bv;
    }
}

// ---------------------------------------------------------------------------
extern "C" void kernel_launch(void* const* d_in, const int* in_sizes, int n_in,
                              void* d_out, int out_size, void* d_ws, size_t ws_size,
                              hipStream_t stream) {
    const float* x    = (const float*)d_in[0];
    const float* ker  = (const float*)d_in[1];
    const float* bias = (const float*)d_in[2];
    const float* wf   = (const float*)d_in[3];
    const float* wi   = (const float*)d_in[4];
    const float* Dre  = (const float*)d_in[5];
    const float* Dim  = (const float*)d_in[6];
    float* out = (float*)d_out;

    // layout: yhb 44.7MB | Ab 4.2MB | zh_T 11.2MB.
    // Xfb (8.4MB) + wfT (698KB, at zhT+8.39MB) alias zh_T: both dead once
    // k_gemm writes zhT. wiT (698KB) aliases yhb base: written after k_gemm
    // (yhb dead), read by k_inv2.
    char* ws = (char*)d_ws;
    u32*    yhb = (u32*)ws;
    u16*    Ab  = (u16*)(ws + 44695552);
    float*  zhT = (float*)(ws + 44695552 + 4194304);
    u32*    Xfb = (u32*)zhT;                                    // disjoint lifetime vs zh_T
    float*  wfT = (float*)(ws + 44695552 + 4194304 + 8388608);  // zhT tail, pre-gemm
    float*  wiT = (float*)ws;                                   // yhb region, post-gemm

    hipLaunchKernelGGL(k_fft_fwd, dim3(4096),  dim3(512), 0, stream, x, Xfb);
    hipLaunchKernelGGL(k_wtr,     dim3(22, 8), dim3(256), 0, stream, wf, wfT);
    hipLaunchKernelGGL(k_prep_B,  dim3(682),   dim3(256), 0, stream, Dre, Dim, ker, yhb);
    hipLaunchKernelGGL(k_beta_A,  dim3(2048),  dim3(256), 0, stream, Xfb, wfT, Ab);
    hipLaunchKernelGGL(k_gemm,    dim3(1024),  dim3(256), 0, stream, Ab, yhb, zhT);
    hipLaunchKernelGGL(k_wtr,     dim3(22, 8), dim3(256), 0, stream, wi, wiT);
    hipLaunchKernelGGL(k_inv2,    dim3(2048),  dim3(256), 0, stream,
                       (const float2*)zhT, wiT, bias, out);
}